// Round 3
// 294.641 us; speedup vs baseline: 1.0107x; 1.0107x over previous
//
#include <hip/hip_runtime.h>
#include <hip/hip_bf16.h>
#include <cstdint>

// SpatialAttentionModule: x[4,256,64,64] fp32; q=Wq x, k=Wk x, v=Wv x (1x1 conv);
// energy = q^T k per batch (N=4096), softmax over j, out = gamma*(v@attn^T) + x.
//
// Round-5 (2nd resubmit; R1/R2 benches were broker timeouts, no data):
// conflict-free LDS via linear rows + XOR chunk swizzle (T2/G21).
// rocprof R4: SQ_LDS_BANK_CONFLICT=1.99e7, MfmaUtil 15.7, Occ 11% -> LDS-BW
// bound, 3x over the 128B/cyc floor. Old padded layouts were 8-way (V) and
// 4-way (K) conflicted per b128 phase. New: K/V stored linear; the 16B chunk
// index is XOR'd with (row&7). global_load_lds writes linearly (wave-uniform
// base + lane*16), so the swizzle is applied by permuting the per-lane GLOBAL
// source chunk; readers XOR the same key (same involution both sides, m173).
// MFMA layouts (HW-verified, learn_hip m89/m91, dtype-independent):
//   A[m=lane&15][k=quad*8+j], B[k=quad*8+j][n=lane&15], C/D: col=lane&15, row=quad*4+reg.

#define C_DIM 256
#define N_DIM 4096
#define B_DIM 4

typedef _Float16 f16;
typedef f16 f16x8 __attribute__((ext_vector_type(8)));
typedef f16 f16x4 __attribute__((ext_vector_type(4)));
typedef float f32x4 __attribute__((ext_vector_type(4)));

__device__ __forceinline__ void dma16(const f16* g, f16* l) {
  __builtin_amdgcn_global_load_lds(
      (const __attribute__((address_space(1))) unsigned int*)g,
      (__attribute__((address_space(3))) unsigned int*)l, 16, 0, 0);
}

// ---------------- prep: transpose-cast x -> xs fp16 [B*N][256] ----------------
__global__ __launch_bounds__(256) void k_prep_xs(const float* __restrict__ x,
                                                 f16* __restrict__ xs) {
  __shared__ float tile[64][65];
  const int b = blockIdx.z, nb = blockIdx.x * 64, cb = blockIdx.y * 64;
  const float* xb = x + (size_t)b * C_DIM * N_DIM;
  for (int i = threadIdx.x; i < 64 * 64; i += 256) {
    int c = i >> 6, n = i & 63;
    tile[c][n] = xb[(size_t)(cb + c) * N_DIM + nb + n];
  }
  __syncthreads();
  f16* xsb = xs + (size_t)b * N_DIM * C_DIM;
  for (int i = threadIdx.x; i < 64 * 64; i += 256) {
    int n = i >> 6, c = i & 63;
    xsb[(size_t)(nb + n) * C_DIM + cb + c] = (f16)tile[c][n];
  }
}

// ---------------- prep: cast 3 weight matrices -> fp16 [3*256][256] ----------------
__global__ __launch_bounds__(256) void k_cast_w(const float* __restrict__ Wq,
                                                const float* __restrict__ Wk,
                                                const float* __restrict__ Wv,
                                                f16* __restrict__ Wh) {
  int i = blockIdx.x * 256 + threadIdx.x;          // 0 .. 3*65536-1
  int sel = i >> 16, j = i & 65535;
  const float* s = (sel == 0) ? Wq : (sel == 1) ? Wk : Wv;
  Wh[i] = (f16)s[j];
}

// ---------------- QKV projection GEMMs (fp16, K=256) ----------------
// z=0: Qh[g][o] = sum_c Wq[o][c] x[g][c] + bq[o]   (layout [B*N][256])
// z=1: Kh same; z=2: Vh[b][o][j] (layout [B*C][N])
__global__ __launch_bounds__(256) void k_proj(const f16* __restrict__ xs,
                                              const f16* __restrict__ Wh,
                                              const float* __restrict__ bq,
                                              const float* __restrict__ bk,
                                              const float* __restrict__ bv,
                                              f16* __restrict__ Qh,
                                              f16* __restrict__ Kh,
                                              f16* __restrict__ Vh) {
  const int z = blockIdx.y;
  const int w = threadIdx.x >> 6, lane = threadIdx.x & 63;
  const int quad = lane >> 4, li = lane & 15;
  const f16* W = Wh + (size_t)z * 65536;
  const float* bias = (z == 0) ? bq : (z == 1) ? bk : bv;

  if (z < 2) {
    f16* out = (z == 0) ? Qh : Kh;
    const int g0 = (blockIdx.x * 4 + w) * 16;
    f16x8 a[8];
    const f16* arow = xs + (size_t)(g0 + li) * C_DIM + quad * 8;
#pragma unroll
    for (int kf = 0; kf < 8; kf++) a[kf] = *(const f16x8*)(arow + kf * 32);
    for (int ot = 0; ot < 16; ot++) {
      f32x4 acc = {0.f, 0.f, 0.f, 0.f};
      const f16* brow = W + (size_t)(ot * 16 + li) * C_DIM + quad * 8;
#pragma unroll
      for (int kf = 0; kf < 8; kf++) {
        f16x8 bf = *(const f16x8*)(brow + kf * 32);
        acc = __builtin_amdgcn_mfma_f32_16x16x32_f16(a[kf], bf, acc, 0, 0, 0);
      }
      float bb = bias[ot * 16 + li];
      f16* orow = out + (size_t)g0 * C_DIM + ot * 16 + li;
#pragma unroll
      for (int r = 0; r < 4; r++)
        orow[(size_t)(quad * 4 + r) * C_DIM] = (f16)(acc[r] + bb);
    }
  } else {
    const int t = blockIdx.x * 4 + w;
    const int b = t >> 8, j0 = (t & 255) * 16;
    f16x8 bfr[8];
    const f16* brow = xs + (size_t)(b * N_DIM + j0 + li) * C_DIM + quad * 8;
#pragma unroll
    for (int kf = 0; kf < 8; kf++) bfr[kf] = *(const f16x8*)(brow + kf * 32);
    for (int ot = 0; ot < 16; ot++) {
      f32x4 acc = {0.f, 0.f, 0.f, 0.f};
      const f16* arow = W + (size_t)(ot * 16 + li) * C_DIM + quad * 8;
#pragma unroll
      for (int kf = 0; kf < 8; kf++) {
        f16x8 af = *(const f16x8*)(arow + kf * 32);
        acc = __builtin_amdgcn_mfma_f32_16x16x32_f16(af, bfr[kf], acc, 0, 0, 0);
      }
      f16* obase = Vh + ((size_t)(b * C_DIM + ot * 16 + quad * 4)) * N_DIM + j0 + li;
#pragma unroll
      for (int r = 0; r < 4; r++) {
        float bb = bias[ot * 16 + quad * 4 + r];
        obase[(size_t)r * N_DIM] = (f16)(acc[r] + bb);
      }
    }
  }
}

// ---------------- fused attention ----------------
// grid (64,4): 64-query block, batch. 4 waves x 16 query-cols.
// JT=64 keys/tile, NT=64 tiles. DMA staging (global_load_lds, 16B), dbuf.
// LDS layouts (f16 units), linear rows + XOR chunk swizzle (chunk = 8 f16 = 16B):
//   K: [64 rows][256], row r: 16B slot s holds global chunk s^(r&7).
//      DMA span p = 2 rows = 1024B linear; lane l -> row 2p+(l>>5), slot l&31,
//      source chunk (l&31)^((2*it+(l>>5))&7).
//   V: [256 rows][64], row c: slot s holds chunk s^(c&7). Span p = 8 rows;
//      lane l -> row p*8+(l>>3), slot l&7, source chunk (l&7)^(l>>3).
//   P (per wave): [16 i][64 j], row stride 72 f16 (144B = 16 mod 128 -> reads
//      conflict-free, writes 2-way/free).
#define JT 64
#define NT (N_DIM / JT)
#define K0_OFF 0
#define K1_OFF 16384
#define V0_OFF 32768
#define V1_OFF 49152
#define P_OFF  65536
#define PSTR 72
#define SMEM_F16 70144        // 140288 B

__global__ __launch_bounds__(256, 1) void k_attn(const f16* __restrict__ Qh,
                                                 const f16* __restrict__ Kh,
                                                 const f16* __restrict__ Vh,
                                                 const float* __restrict__ x,
                                                 const float* __restrict__ gamma_p,
                                                 float* __restrict__ out) {
  __shared__ __align__(16) f16 smem[SMEM_F16];
  const int b = blockIdx.y;
  const int tid = threadIdx.x;
  const int w = tid >> 6, lane = tid & 63;
  const int quad = lane >> 4, li = lane & 15;
  const int lw = li & 7;
  const int ibase = blockIdx.x * 64 + w * 16;

  // loop-invariant swizzled slot offsets (f16 units), static-indexed
  int ksl[8];
#pragma unroll
  for (int kf = 0; kf < 8; kf++) ksl[kf] = ((kf * 4 + quad) ^ lw) << 3;
  const int vsl0 = (quad ^ lw) << 3;

  // Q fragments (B-operand: n = query col, k = channel)
  f16x8 qf[8];
  {
    const f16* qrow = Qh + (size_t)(b * N_DIM + ibase + li) * C_DIM + quad * 8;
#pragma unroll
    for (int kf = 0; kf < 8; kf++) qf[kf] = *(const f16x8*)(qrow + kf * 32);
  }
  const f16* Kb = Kh + (size_t)b * N_DIM * C_DIM;
  const f16* Vb = Vh + (size_t)b * C_DIM * N_DIM;
  f16* Pw = smem + P_OFF + w * 16 * PSTR;

  const float LOG2E = 1.4426950408889634f;
  float m = -3.0e38f, l = 0.0f;
  f32x4 acc[16];
#pragma unroll
  for (int ct = 0; ct < 16; ct++) acc[ct] = (f32x4){0.f, 0.f, 0.f, 0.f};

  // prologue: DMA tile 0 -> buf0 (pre-swizzled global source chunks)
  {
    const f16* kg = Kb;
    const f16* vg = Vb;
#pragma unroll
    for (int it = 0; it < 8; it++) {
      int p = w * 8 + it;
      int krsw = (2 * it + (lane >> 5)) & 7;
      dma16(kg + (size_t)(2 * p + (lane >> 5)) * C_DIM + (((lane & 31) ^ krsw) * 8),
            smem + K0_OFF + p * 512);
      dma16(vg + (size_t)(p * 8 + (lane >> 3)) * N_DIM + (((lane & 7) ^ (lane >> 3)) * 8),
            smem + V0_OFF + p * 512);
    }
  }
  __syncthreads();

  for (int t = 0; t < NT; t++) {
    const f16* Kc = smem + ((t & 1) ? K1_OFF : K0_OFF);
    const f16* Vc = smem + ((t & 1) ? V1_OFF : V0_OFF);

    // issue DMA for tile t+1 into the other buffer (drained at the barrier)
    if (t + 1 < NT) {
      f16* Kn = smem + ((t & 1) ? K0_OFF : K1_OFF);
      f16* Vn = smem + ((t & 1) ? V0_OFF : V1_OFF);
      const int jt = (t + 1) * JT;
      const f16* kg = Kb + (size_t)jt * C_DIM;
      const f16* vg = Vb + jt;
#pragma unroll
      for (int it = 0; it < 8; it++) {
        int p = w * 8 + it;
        int krsw = (2 * it + (lane >> 5)) & 7;
        dma16(kg + (size_t)(2 * p + (lane >> 5)) * C_DIM + (((lane & 31) ^ krsw) * 8),
              Kn + p * 512);
        dma16(vg + (size_t)(p * 8 + (lane >> 3)) * N_DIM + (((lane & 7) ^ (lane >> 3)) * 8),
              Vn + p * 512);
      }
    }

    // ---- S^T: rows j (sub*16 + quad*4 + reg), cols i (lane&15) ----
    f32x4 s[4];
#pragma unroll
    for (int sub = 0; sub < 4; sub++) {
      f32x4 ss = {0.f, 0.f, 0.f, 0.f};
      const f16* krow = Kc + (sub * 16 + li) * 256;
#pragma unroll
      for (int kf = 0; kf < 8; kf++) {
        f16x8 kfr = *(const f16x8*)(krow + ksl[kf]);
        ss = __builtin_amdgcn_mfma_f32_16x16x32_f16(kfr, qf[kf], ss, 0, 0, 0);
      }
      s[sub] = ss;
    }

    // ---- online softmax (per query col li) ----
    float tm = -3.0e38f;
#pragma unroll
    for (int sub = 0; sub < 4; sub++)
      tm = fmaxf(tm, fmaxf(fmaxf(s[sub][0], s[sub][1]), fmaxf(s[sub][2], s[sub][3])));
    tm = fmaxf(tm, __shfl_xor(tm, 16));
    tm = fmaxf(tm, __shfl_xor(tm, 32));
    float nm = fmaxf(m, tm);
    float alpha = exp2f((m - nm) * LOG2E);
    m = nm;
    if (__any(alpha < 1.0f)) {      // wave-uniform skip when max unchanged
      l *= alpha;
#pragma unroll
      for (int ct = 0; ct < 16; ct++) {
        acc[ct][0] *= alpha; acc[ct][1] *= alpha;
        acc[ct][2] *= alpha; acc[ct][3] *= alpha;
      }
    }
#pragma unroll
    for (int sub = 0; sub < 4; sub++) {
      float p0 = exp2f((s[sub][0] - m) * LOG2E);
      float p1 = exp2f((s[sub][1] - m) * LOG2E);
      float p2 = exp2f((s[sub][2] - m) * LOG2E);
      float p3 = exp2f((s[sub][3] - m) * LOG2E);
      l += (p0 + p1) + (p2 + p3);
      *(f16x4*)(Pw + li * PSTR + sub * 16 + quad * 4) =
          (f16x4){(f16)p0, (f16)p1, (f16)p2, (f16)p3};
    }

    // ---- PV: O^T[c][i] += V[c][j] P^T[j][i] (k = j, two 32-chunks) ----
    f16x8 pf0 = *(const f16x8*)(Pw + li * PSTR + quad * 8);
    f16x8 pf1 = *(const f16x8*)(Pw + li * PSTR + 32 + quad * 8);
#pragma unroll
    for (int ct = 0; ct < 16; ct++) {
      const f16* vrow = Vc + (ct * 16 + li) * 64;
      f16x8 v0 = *(const f16x8*)(vrow + vsl0);
      f16x8 v1 = *(const f16x8*)(vrow + (vsl0 ^ 32));
      acc[ct] = __builtin_amdgcn_mfma_f32_16x16x32_f16(v0, pf0, acc[ct], 0, 0, 0);
      acc[ct] = __builtin_amdgcn_mfma_f32_16x16x32_f16(v1, pf1, acc[ct], 0, 0, 0);
    }

    __syncthreads();   // waits readers of current bufs AND drains next-tile DMA
  }

  l += __shfl_xor(l, 16);
  l += __shfl_xor(l, 32);
  const float scale = gamma_p[0] / l;

  const float* xb = x + (size_t)b * C_DIM * N_DIM;
  float* ob = out + (size_t)b * C_DIM * N_DIM;
  const int icol = ibase + li;
#pragma unroll
  for (int ct = 0; ct < 16; ct++) {
#pragma unroll
    for (int r = 0; r < 4; r++) {
      size_t off = (size_t)(ct * 16 + quad * 4 + r) * N_DIM + icol;
      ob[off] = acc[ct][r] * scale + xb[off];
    }
  }
}

extern "C" void kernel_launch(void* const* d_in, const int* in_sizes, int n_in,
                              void* d_out, int out_size, void* d_ws, size_t ws_size,
                              hipStream_t stream) {
  const float* x     = (const float*)d_in[0];
  const float* Wq    = (const float*)d_in[1];
  const float* bq    = (const float*)d_in[2];
  const float* Wk    = (const float*)d_in[3];
  const float* bk    = (const float*)d_in[4];
  const float* Wv    = (const float*)d_in[5];
  const float* bv    = (const float*)d_in[6];
  const float* gamma = (const float*)d_in[7];
  float* out = (float*)d_out;

  // workspace: xs 8MB | Qh 8MB | Kh 8MB | Vh 8MB | Wh 384KB  (~32.4 MB)
  char* ws = (char*)d_ws;
  f16* xs = (f16*)(ws);
  f16* Qh = (f16*)(ws + (size_t)8  * 1024 * 1024);
  f16* Kh = (f16*)(ws + (size_t)16 * 1024 * 1024);
  f16* Vh = (f16*)(ws + (size_t)24 * 1024 * 1024);
  f16* Wh = (f16*)(ws + (size_t)32 * 1024 * 1024);

  k_prep_xs<<<dim3(64, 4, 4), 256, 0, stream>>>(x, xs);
  k_cast_w<<<dim3(768), 256, 0, stream>>>(Wq, Wk, Wv, Wh);
  k_proj<<<dim3(256, 3), 256, 0, stream>>>(xs, Wh, bq, bk, bv, Qh, Kh, Vh);
  k_attn<<<dim3(64, 4), 256, 0, stream>>>(Qh, Kh, Vh, x, gamma, out);
}

// Round 6
// 258.596 us; speedup vs baseline: 1.1516x; 1.1394x over previous
//
#include <hip/hip_runtime.h>
#include <hip/hip_bf16.h>
#include <cstdint>

// SpatialAttentionModule: x[4,256,64,64] fp32; q=Wq x, k=Wk x, v=Wv x (1x1 conv);
// energy = q^T k per batch (N=4096), softmax over j, out = gamma*(v@attn^T) + x.
//
// Round-6 (3rd submit; R4/R5 benches were broker timeouts, no data): occupancy
// fix. R5(meas) result: conflicts halved (1.99e7->9.96e6) but time unchanged
// (178us) -> NOT LDS-conflict-bound. Occupancy=11% = 1 wave/SIMD (grid 256
// blocks = CU count, 4 waves/block): latency-bound, serial stalls exposed.
// Fix: 8-wave (512-thr) blocks, j-split — wave pair (w, w+4) handles the same
// 16 query cols but opposite 32-key halves of each tile, each with its own
// online-softmax state; partials merged once via LDS at the end.
// -> 8 waves/CU = 2/SIMD, per-wave serial work halved, same LDS traffic.
// LDS K/V layouts unchanged (linear + XOR chunk swizzle, conflict-free).
// MFMA layouts (HW-verified, learn_hip m89/m91, dtype-independent):
//   A[m=lane&15][k=quad*8+j], B[k=quad*8+j][n=lane&15], C/D: col=lane&15, row=quad*4+reg.

#define C_DIM 256
#define N_DIM 4096
#define B_DIM 4

typedef _Float16 f16;
typedef f16 f16x8 __attribute__((ext_vector_type(8)));
typedef f16 f16x4 __attribute__((ext_vector_type(4)));
typedef float f32x4 __attribute__((ext_vector_type(4)));

__device__ __forceinline__ void dma16(const f16* g, f16* l) {
  __builtin_amdgcn_global_load_lds(
      (const __attribute__((address_space(1))) unsigned int*)g,
      (__attribute__((address_space(3))) unsigned int*)l, 16, 0, 0);
}

// ---------------- prep: transpose-cast x -> xs fp16 [B*N][256] ----------------
__global__ __launch_bounds__(256) void k_prep_xs(const float* __restrict__ x,
                                                 f16* __restrict__ xs) {
  __shared__ float tile[64][65];
  const int b = blockIdx.z, nb = blockIdx.x * 64, cb = blockIdx.y * 64;
  const float* xb = x + (size_t)b * C_DIM * N_DIM;
  for (int i = threadIdx.x; i < 64 * 64; i += 256) {
    int c = i >> 6, n = i & 63;
    tile[c][n] = xb[(size_t)(cb + c) * N_DIM + nb + n];
  }
  __syncthreads();
  f16* xsb = xs + (size_t)b * N_DIM * C_DIM;
  for (int i = threadIdx.x; i < 64 * 64; i += 256) {
    int n = i >> 6, c = i & 63;
    xsb[(size_t)(nb + n) * C_DIM + cb + c] = (f16)tile[c][n];
  }
}

// ---------------- prep: cast 3 weight matrices -> fp16 [3*256][256] ----------------
__global__ __launch_bounds__(256) void k_cast_w(const float* __restrict__ Wq,
                                                const float* __restrict__ Wk,
                                                const float* __restrict__ Wv,
                                                f16* __restrict__ Wh) {
  int i = blockIdx.x * 256 + threadIdx.x;          // 0 .. 3*65536-1
  int sel = i >> 16, j = i & 65535;
  const float* s = (sel == 0) ? Wq : (sel == 1) ? Wk : Wv;
  Wh[i] = (f16)s[j];
}

// ---------------- QKV projection GEMMs (fp16, K=256) ----------------
// z=0: Qh[g][o] = sum_c Wq[o][c] x[g][c] + bq[o]   (layout [B*N][256])
// z=1: Kh same; z=2: Vh[b][o][j] (layout [B*C][N])
__global__ __launch_bounds__(256) void k_proj(const f16* __restrict__ xs,
                                              const f16* __restrict__ Wh,
                                              const float* __restrict__ bq,
                                              const float* __restrict__ bk,
                                              const float* __restrict__ bv,
                                              f16* __restrict__ Qh,
                                              f16* __restrict__ Kh,
                                              f16* __restrict__ Vh) {
  const int z = blockIdx.y;
  const int w = threadIdx.x >> 6, lane = threadIdx.x & 63;
  const int quad = lane >> 4, li = lane & 15;
  const f16* W = Wh + (size_t)z * 65536;
  const float* bias = (z == 0) ? bq : (z == 1) ? bk : bv;

  if (z < 2) {
    f16* out = (z == 0) ? Qh : Kh;
    const int g0 = (blockIdx.x * 4 + w) * 16;
    f16x8 a[8];
    const f16* arow = xs + (size_t)(g0 + li) * C_DIM + quad * 8;
#pragma unroll
    for (int kf = 0; kf < 8; kf++) a[kf] = *(const f16x8*)(arow + kf * 32);
    for (int ot = 0; ot < 16; ot++) {
      f32x4 acc = {0.f, 0.f, 0.f, 0.f};
      const f16* brow = W + (size_t)(ot * 16 + li) * C_DIM + quad * 8;
#pragma unroll
      for (int kf = 0; kf < 8; kf++) {
        f16x8 bf = *(const f16x8*)(brow + kf * 32);
        acc = __builtin_amdgcn_mfma_f32_16x16x32_f16(a[kf], bf, acc, 0, 0, 0);
      }
      float bb = bias[ot * 16 + li];
      f16* orow = out + (size_t)g0 * C_DIM + ot * 16 + li;
#pragma unroll
      for (int r = 0; r < 4; r++)
        orow[(size_t)(quad * 4 + r) * C_DIM] = (f16)(acc[r] + bb);
    }
  } else {
    const int t = blockIdx.x * 4 + w;
    const int b = t >> 8, j0 = (t & 255) * 16;
    f16x8 bfr[8];
    const f16* brow = xs + (size_t)(b * N_DIM + j0 + li) * C_DIM + quad * 8;
#pragma unroll
    for (int kf = 0; kf < 8; kf++) bfr[kf] = *(const f16x8*)(brow + kf * 32);
    for (int ot = 0; ot < 16; ot++) {
      f32x4 acc = {0.f, 0.f, 0.f, 0.f};
      const f16* arow = W + (size_t)(ot * 16 + li) * C_DIM + quad * 8;
#pragma unroll
      for (int kf = 0; kf < 8; kf++) {
        f16x8 af = *(const f16x8*)(arow + kf * 32);
        acc = __builtin_amdgcn_mfma_f32_16x16x32_f16(af, bfr[kf], acc, 0, 0, 0);
      }
      f16* obase = Vh + ((size_t)(b * C_DIM + ot * 16 + quad * 4)) * N_DIM + j0 + li;
#pragma unroll
      for (int r = 0; r < 4; r++) {
        float bb = bias[ot * 16 + quad * 4 + r];
        obase[(size_t)r * N_DIM] = (f16)(acc[r] + bb);
      }
    }
  }
}

// ---------------- fused attention ----------------
// grid (64,4): 64-query block, batch. 8 waves: wq=w&3 (16 query cols each),
// wj=w>>2 (j-half of each 64-key tile). Pair (w, w+4) merges at the end.
// JT=64 keys/tile, NT=64 tiles. DMA staging (global_load_lds, 16B), dbuf.
// LDS layouts (f16 units), linear rows + XOR chunk swizzle (chunk = 8 f16 = 16B):
//   K: [64 rows][256], row r: 16B slot s holds global chunk s^(r&7).
//      DMA span p (0..31) = 2 rows = 1024B linear; lane l -> row 2p+(l>>5),
//      slot l&31, source chunk (l&31)^((2p+(l>>5))&7); p = w*4+it.
//   V: [256 rows][64], row c: slot s holds chunk s^(c&7). Span p = 8 rows;
//      lane l -> row p*8+(l>>3), slot l&7, source chunk (l&7)^(l>>3).
//   P (per wave): [16 i][32 j], row stride 40 f16 (80B; 80=16*5, odd multiple
//      of 16 -> reads/writes conflict-free).
// Merge scratch (after loop, reuses K/V region as f32):
//   per upper wave u: 16 cols x 260 f32 (col stride 1040B = 16 mod 128);
//   m/l at f32 offset 4*4160.
#define JT 64
#define NT (N_DIM / JT)
#define K0_OFF 0
#define K1_OFF 16384
#define V0_OFF 32768
#define V1_OFF 49152
#define P_OFF  65536
#define PSTR 40
#define SMEM_F16 70656        // 141312 B
#define MRG_WSTR 4160         // f32 per upper wave (16 cols * 260)
#define MRG_CSTR 260          // f32 col stride
#define ML_OFF   16640        // 4*4160

__global__ __launch_bounds__(512, 1) void k_attn(const f16* __restrict__ Qh,
                                                 const f16* __restrict__ Kh,
                                                 const f16* __restrict__ Vh,
                                                 const float* __restrict__ x,
                                                 const float* __restrict__ gamma_p,
                                                 float* __restrict__ out) {
  __shared__ __align__(16) f16 smem[SMEM_F16];
  const int b = blockIdx.y;
  const int tid = threadIdx.x;
  const int w = tid >> 6, lane = tid & 63;
  const int wq = w & 3, wj = w >> 2;
  const int quad = lane >> 4, li = lane & 15;
  const int lw = li & 7;
  const int ibase = blockIdx.x * 64 + wq * 16;

  // loop-invariant swizzled slot offsets (f16 units), static-indexed
  int ksl[8];
#pragma unroll
  for (int kf = 0; kf < 8; kf++) ksl[kf] = ((kf * 4 + quad) ^ lw) << 3;
  const int vsl = ((wj * 4 + quad) ^ lw) << 3;   // V j-chunk for this wave's half

  // Q fragments (B-operand: n = query col, k = channel)
  f16x8 qf[8];
  {
    const f16* qrow = Qh + (size_t)(b * N_DIM + ibase + li) * C_DIM + quad * 8;
#pragma unroll
    for (int kf = 0; kf < 8; kf++) qf[kf] = *(const f16x8*)(qrow + kf * 32);
  }
  const f16* Kb = Kh + (size_t)b * N_DIM * C_DIM;
  const f16* Vb = Vh + (size_t)b * C_DIM * N_DIM;
  f16* Pw = smem + P_OFF + w * 16 * PSTR;

  const float LOG2E = 1.4426950408889634f;
  float m = -3.0e38f, l = 0.0f;
  f32x4 acc[16];
#pragma unroll
  for (int ct = 0; ct < 16; ct++) acc[ct] = (f32x4){0.f, 0.f, 0.f, 0.f};

  // prologue: DMA tile 0 -> buf0 (pre-swizzled global source chunks)
  {
#pragma unroll
    for (int it = 0; it < 4; it++) {
      int p = w * 4 + it;
      int krsw = (2 * it + (lane >> 5)) & 7;     // (2p+(l>>5))&7, since 8w==0 mod 8
      dma16(Kb + (size_t)(2 * p + (lane >> 5)) * C_DIM + (((lane & 31) ^ krsw) * 8),
            smem + K0_OFF + p * 512);
      dma16(Vb + (size_t)(p * 8 + (lane >> 3)) * N_DIM + (((lane & 7) ^ (lane >> 3)) * 8),
            smem + V0_OFF + p * 512);
    }
  }
  __syncthreads();

  for (int t = 0; t < NT; t++) {
    const f16* Kc = smem + ((t & 1) ? K1_OFF : K0_OFF);
    const f16* Vc = smem + ((t & 1) ? V1_OFF : V0_OFF);

    // issue DMA for tile t+1 into the other buffer (drained at the barrier)
    if (t + 1 < NT) {
      f16* Kn = smem + ((t & 1) ? K0_OFF : K1_OFF);
      f16* Vn = smem + ((t & 1) ? V0_OFF : V1_OFF);
      const int jt = (t + 1) * JT;
      const f16* kg = Kb + (size_t)jt * C_DIM;
      const f16* vg = Vb + jt;
#pragma unroll
      for (int it = 0; it < 4; it++) {
        int p = w * 4 + it;
        int krsw = (2 * it + (lane >> 5)) & 7;
        dma16(kg + (size_t)(2 * p + (lane >> 5)) * C_DIM + (((lane & 31) ^ krsw) * 8),
              Kn + p * 512);
        dma16(vg + (size_t)(p * 8 + (lane >> 3)) * N_DIM + (((lane & 7) ^ (lane >> 3)) * 8),
              Vn + p * 512);
      }
    }

    // ---- S^T for this wave's j-half: rows j = wj*32 + sub*16 + (quad*4+reg) ----
    f32x4 s[2];
#pragma unroll
    for (int sub = 0; sub < 2; sub++) {
      f32x4 ss = {0.f, 0.f, 0.f, 0.f};
      const f16* krow = Kc + (wj * 32 + sub * 16 + li) * 256;  // row&7 == li&7
#pragma unroll
      for (int kf = 0; kf < 8; kf++) {
        f16x8 kfr = *(const f16x8*)(krow + ksl[kf]);
        ss = __builtin_amdgcn_mfma_f32_16x16x32_f16(kfr, qf[kf], ss, 0, 0, 0);
      }
      s[sub] = ss;
    }

    // ---- online softmax over this j-half (per query col li) ----
    float tm = fmaxf(fmaxf(fmaxf(s[0][0], s[0][1]), fmaxf(s[0][2], s[0][3])),
                     fmaxf(fmaxf(s[1][0], s[1][1]), fmaxf(s[1][2], s[1][3])));
    tm = fmaxf(tm, __shfl_xor(tm, 16));
    tm = fmaxf(tm, __shfl_xor(tm, 32));
    float nm = fmaxf(m, tm);
    float alpha = exp2f((m - nm) * LOG2E);
    m = nm;
    if (__any(alpha < 1.0f)) {      // wave-uniform skip when max unchanged
      l *= alpha;
#pragma unroll
      for (int ct = 0; ct < 16; ct++) {
        acc[ct][0] *= alpha; acc[ct][1] *= alpha;
        acc[ct][2] *= alpha; acc[ct][3] *= alpha;
      }
    }
#pragma unroll
    for (int sub = 0; sub < 2; sub++) {
      float p0 = exp2f((s[sub][0] - m) * LOG2E);
      float p1 = exp2f((s[sub][1] - m) * LOG2E);
      float p2 = exp2f((s[sub][2] - m) * LOG2E);
      float p3 = exp2f((s[sub][3] - m) * LOG2E);
      l += (p0 + p1) + (p2 + p3);
      *(f16x4*)(Pw + li * PSTR + sub * 16 + quad * 4) =
          (f16x4){(f16)p0, (f16)p1, (f16)p2, (f16)p3};
    }

    // ---- PV (half): O^T[c][i] += V[c][j-half] P^T[j-half][i], k = 32 ----
    f16x8 pf = *(const f16x8*)(Pw + li * PSTR + quad * 8);
#pragma unroll
    for (int ct = 0; ct < 16; ct++) {
      const f16* vrow = Vc + (ct * 16 + li) * 64;
      f16x8 v = *(const f16x8*)(vrow + vsl);
      acc[ct] = __builtin_amdgcn_mfma_f32_16x16x32_f16(v, pf, acc[ct], 0, 0, 0);
    }

    __syncthreads();   // waits readers of current bufs AND drains next-tile DMA
  }

  // ---- reduce l across quads; merge j-half partials via LDS (K/V region reused) ----
  l += __shfl_xor(l, 16);
  l += __shfl_xor(l, 32);

  float* mrg = (float*)smem;
  if (wj == 1) {
    const int u = wq;
    float* base = mrg + u * MRG_WSTR + li * MRG_CSTR;
#pragma unroll
    for (int ct = 0; ct < 16; ct++)
      *(f32x4*)(base + ct * 16 + quad * 4) = acc[ct];
    if (lane < 16) {
      mrg[ML_OFF + u * 32 + li] = m;
      mrg[ML_OFF + u * 32 + 16 + li] = l;
    }
  }
  __syncthreads();
  if (wj == 0) {
    const int u = wq;
    const float m_b = mrg[ML_OFF + u * 32 + li];
    const float l_b = mrg[ML_OFF + u * 32 + 16 + li];
    const float M = fmaxf(m, m_b);
    const float aa = exp2f((m - M) * LOG2E);
    const float ab = exp2f((m_b - M) * LOG2E);
    const float lm = aa * l + ab * l_b;
    const float scale = gamma_p[0] / lm;
    const float* base = mrg + u * MRG_WSTR + li * MRG_CSTR;

    const float* xb = x + (size_t)b * C_DIM * N_DIM;
    float* ob = out + (size_t)b * C_DIM * N_DIM;
    const int icol = ibase + li;
#pragma unroll
    for (int ct = 0; ct < 16; ct++) {
      f32x4 accb = *(const f32x4*)(base + ct * 16 + quad * 4);
#pragma unroll
      for (int r = 0; r < 4; r++) {
        size_t off = (size_t)(ct * 16 + quad * 4 + r) * N_DIM + icol;
        ob[off] = (acc[ct][r] * aa + accb[r] * ab) * scale + xb[off];
      }
    }
  }
}

extern "C" void kernel_launch(void* const* d_in, const int* in_sizes, int n_in,
                              void* d_out, int out_size, void* d_ws, size_t ws_size,
                              hipStream_t stream) {
  const float* x     = (const float*)d_in[0];
  const float* Wq    = (const float*)d_in[1];
  const float* bq    = (const float*)d_in[2];
  const float* Wk    = (const float*)d_in[3];
  const float* bk    = (const float*)d_in[4];
  const float* Wv    = (const float*)d_in[5];
  const float* bv    = (const float*)d_in[6];
  const float* gamma = (const float*)d_in[7];
  float* out = (float*)d_out;

  // workspace: xs 8MB | Qh 8MB | Kh 8MB | Vh 8MB | Wh 384KB  (~32.4 MB)
  char* ws = (char*)d_ws;
  f16* xs = (f16*)(ws);
  f16* Qh = (f16*)(ws + (size_t)8  * 1024 * 1024);
  f16* Kh = (f16*)(ws + (size_t)16 * 1024 * 1024);
  f16* Vh = (f16*)(ws + (size_t)24 * 1024 * 1024);
  f16* Wh = (f16*)(ws + (size_t)32 * 1024 * 1024);

  k_prep_xs<<<dim3(64, 4, 4), 256, 0, stream>>>(x, xs);
  k_cast_w<<<dim3(768), 256, 0, stream>>>(Wq, Wk, Wv, Wh);
  k_proj<<<dim3(256, 3), 256, 0, stream>>>(xs, Wh, bq, bk, bv, Qh, Kh, Vh);
  k_attn<<<dim3(64, 4), 512, 0, stream>>>(Qh, Kh, Vh, x, gamma, out);
}

// Round 8
// 250.993 us; speedup vs baseline: 1.1865x; 1.0303x over previous
//
#include <hip/hip_runtime.h>
#include <hip/hip_bf16.h>
#include <cstdint>

// SpatialAttentionModule: x[4,256,64,64] fp32; q=Wq x, k=Wk x, v=Wv x (1x1 conv);
// energy = q^T k per batch (N=4096), softmax over j, out = gamma*(v@attn^T) + x.
//
// Round-7 (resubmit; R7 bench was a broker timeout, no data): prep-path fusion.
// R6 measured: k_attn 139.9us (8-wave j-split, Occ 21%, +27% vs R5) but total
// 258.6 -> ~119us is prep (k_prep_xs+k_cast_w+k_proj+launch overhead), now 46%
// of total. Fix: fuse prep into one k_qkv:
//  - stage x-tile to LDS xt[64g][256c] f16 (XOR chunk swizzle, same as k_attn)
//  - ONE x-fragment set serves as MFMA-A and MFMA-B (identical reg layouts)
//  - Q/K: mfma(W, x) -> D[o][g], store f16x4 at consecutive o
//  - V:   mfma(x, W) -> D[g][o], store f16x4 at consecutive j
//  -> all stores vectorized (old k_proj: scalar 2B stores), xs roundtrip gone,
//     one fewer launch. k_attn byte-identical to R6 (delta attribution).
// MFMA layouts (HW-verified, learn_hip m89/m91, dtype-independent):
//   A[m=lane&15][k=quad*8+j], B[k=quad*8+j][n=lane&15], C/D: col=lane&15, row=quad*4+reg.

#define C_DIM 256
#define N_DIM 4096
#define B_DIM 4

typedef _Float16 f16;
typedef f16 f16x8 __attribute__((ext_vector_type(8)));
typedef f16 f16x4 __attribute__((ext_vector_type(4)));
typedef float f32x4 __attribute__((ext_vector_type(4)));

__device__ __forceinline__ void dma16(const f16* g, f16* l) {
  __builtin_amdgcn_global_load_lds(
      (const __attribute__((address_space(1))) unsigned int*)g,
      (__attribute__((address_space(3))) unsigned int*)l, 16, 0, 0);
}

// ---------------- prep: cast 3 weight matrices -> fp16 [3*256][256] ----------------
__global__ __launch_bounds__(256) void k_cast_w(const float* __restrict__ Wq,
                                                const float* __restrict__ Wk,
                                                const float* __restrict__ Wv,
                                                f16* __restrict__ Wh) {
  int i = blockIdx.x * 256 + threadIdx.x;          // 0 .. 3*65536-1
  int sel = i >> 16, j = i & 65535;
  const float* s = (sel == 0) ? Wq : (sel == 1) ? Wk : Wv;
  Wh[i] = (f16)s[j];
}

// ---------------- fused QKV projection ----------------
// grid (64, 4) = (n-tile, batch), 512 threads = 8 waves.
// Stage: x[b][0:256][n0:n0+64] -> LDS xt[64 g][256 c] f16, chunk-XOR swizzle
//   (16B chunk s of row g holds global chunk s^(g&7)); wave w loads c-rows
//   w*32..w*32+31 (fully coalesced 256B per row), packs f16x8, ds_write_b128.
// Compute: wave w: gtile gt=w&3 (g = n0+gt*16+li), role=w>>2.
//   x-frags xf[8] read once (conflict-free via XOR slots).
//   role 0: Q (16 ot) + V ot 0..7 ; role 1: K (16 ot) + V ot 8..15.
//   Q/K: acc=mfma(Wfrag, xf) -> D[o=ot*16+quad*4+r][g=li]
//        -> store f16x4 at Qh[(g)*256 + ot*16+quad*4] (r consecutive).
//   V:   acc=mfma(xf, Wfrag) -> D[g=gt*16+quad*4+r][o=ot*16+li]
//        -> store f16x4 at Vh[(b*256+o)*4096 + n0+gt*16+quad*4] (r consecutive).
__global__ __launch_bounds__(512) void k_qkv(const float* __restrict__ x,
                                             const f16* __restrict__ Wh,
                                             const float* __restrict__ bq,
                                             const float* __restrict__ bk,
                                             const float* __restrict__ bv,
                                             f16* __restrict__ Qh,
                                             f16* __restrict__ Kh,
                                             f16* __restrict__ Vh) {
  __shared__ __align__(16) f16 xt[64 * 256];   // 32 KiB
  const int b = blockIdx.y, n0 = blockIdx.x * 64;
  const int tid = threadIdx.x;
  const int w = tid >> 6, lane = tid & 63;
  const int quad = lane >> 4, li = lane & 15;
  const int gt = w & 3, role = w >> 2;

  // ---- stage x tile (fp32 -> f16, swizzled) ----
  {
    const float* xb = x + (size_t)b * C_DIM * N_DIM + n0;
#pragma unroll
    for (int cg = 0; cg < 4; cg++) {
      f16x8 v;
#pragma unroll
      for (int j = 0; j < 8; j++) {
        int c = w * 32 + cg * 8 + j;
        v[j] = (f16)xb[(size_t)c * N_DIM + lane];
      }
      int chunk = w * 4 + cg;
      int slot = chunk ^ (lane & 7);
      *(f16x8*)(&xt[lane * 256 + slot * 8]) = v;
    }
  }
  __syncthreads();

  // ---- x fragments (shared by A- and B-roles) ----
  int xsl[8];
#pragma unroll
  for (int kf = 0; kf < 8; kf++) xsl[kf] = ((kf * 4 + quad) ^ (li & 7)) << 3;
  f16x8 xf[8];
  {
    const f16* xrow = xt + (gt * 16 + li) * 256;
#pragma unroll
    for (int kf = 0; kf < 8; kf++) xf[kf] = *(const f16x8*)(xrow + xsl[kf]);
  }

  // ---- Q or K: out[g][o], D rows = o ----
  {
    const f16* W = Wh + (size_t)role * 65536;
    const float* bias = role ? bk : bq;
    f16* out = role ? Kh : Qh;
    const size_t grow = (size_t)(b * N_DIM + n0 + gt * 16 + li) * C_DIM;
    for (int ot = 0; ot < 16; ot++) {
      f32x4 acc = {0.f, 0.f, 0.f, 0.f};
      const f16* wrow = W + (size_t)(ot * 16 + li) * C_DIM + quad * 8;
#pragma unroll
      for (int kf = 0; kf < 8; kf++) {
        f16x8 wf = *(const f16x8*)(wrow + kf * 32);
        acc = __builtin_amdgcn_mfma_f32_16x16x32_f16(wf, xf[kf], acc, 0, 0, 0);
      }
      const int o0 = ot * 16 + quad * 4;
      f16x4 st = {(f16)(acc[0] + bias[o0]), (f16)(acc[1] + bias[o0 + 1]),
                  (f16)(acc[2] + bias[o0 + 2]), (f16)(acc[3] + bias[o0 + 3])};
      *(f16x4*)(out + grow + o0) = st;
    }
  }

  // ---- V half: out[o][j], D rows = j ----
  {
    const f16* W = Wh + (size_t)2 * 65536;
#pragma unroll
    for (int ot8 = 0; ot8 < 8; ot8++) {
      const int ot = role * 8 + ot8;
      f32x4 acc = {0.f, 0.f, 0.f, 0.f};
      const f16* wrow = W + (size_t)(ot * 16 + li) * C_DIM + quad * 8;
#pragma unroll
      for (int kf = 0; kf < 8; kf++) {
        f16x8 wf = *(const f16x8*)(wrow + kf * 32);
        acc = __builtin_amdgcn_mfma_f32_16x16x32_f16(xf[kf], wf, acc, 0, 0, 0);
      }
      const float bb = bv[ot * 16 + li];
      f16x4 st = {(f16)(acc[0] + bb), (f16)(acc[1] + bb),
                  (f16)(acc[2] + bb), (f16)(acc[3] + bb)};
      *(f16x4*)(Vh + (size_t)(b * C_DIM + ot * 16 + li) * N_DIM +
                n0 + gt * 16 + quad * 4) = st;
    }
  }
}

// ---------------- fused attention (byte-identical to R6) ----------------
// grid (64,4): 64-query block, batch. 8 waves: wq=w&3 (16 query cols each),
// wj=w>>2 (j-half of each 64-key tile). Pair (w, w+4) merges at the end.
// JT=64 keys/tile, NT=64 tiles. DMA staging (global_load_lds, 16B), dbuf.
// LDS layouts (f16 units), linear rows + XOR chunk swizzle (chunk = 8 f16 = 16B):
//   K: [64 rows][256], row r: 16B slot s holds global chunk s^(r&7).
//   V: [256 rows][64], row c: slot s holds chunk s^(c&7).
//   P (per wave): [16 i][32 j], row stride 40 f16 (80B, conflict-free).
#define JT 64
#define NT (N_DIM / JT)
#define K0_OFF 0
#define K1_OFF 16384
#define V0_OFF 32768
#define V1_OFF 49152
#define P_OFF  65536
#define PSTR 40
#define SMEM_F16 70656        // 141312 B
#define MRG_WSTR 4160         // f32 per upper wave (16 cols * 260)
#define MRG_CSTR 260          // f32 col stride
#define ML_OFF   16640        // 4*4160

__global__ __launch_bounds__(512, 1) void k_attn(const f16* __restrict__ Qh,
                                                 const f16* __restrict__ Kh,
                                                 const f16* __restrict__ Vh,
                                                 const float* __restrict__ x,
                                                 const float* __restrict__ gamma_p,
                                                 float* __restrict__ out) {
  __shared__ __align__(16) f16 smem[SMEM_F16];
  const int b = blockIdx.y;
  const int tid = threadIdx.x;
  const int w = tid >> 6, lane = tid & 63;
  const int wq = w & 3, wj = w >> 2;
  const int quad = lane >> 4, li = lane & 15;
  const int lw = li & 7;
  const int ibase = blockIdx.x * 64 + wq * 16;

  // loop-invariant swizzled slot offsets (f16 units), static-indexed
  int ksl[8];
#pragma unroll
  for (int kf = 0; kf < 8; kf++) ksl[kf] = ((kf * 4 + quad) ^ lw) << 3;
  const int vsl = ((wj * 4 + quad) ^ lw) << 3;   // V j-chunk for this wave's half

  // Q fragments (B-operand: n = query col, k = channel)
  f16x8 qf[8];
  {
    const f16* qrow = Qh + (size_t)(b * N_DIM + ibase + li) * C_DIM + quad * 8;
#pragma unroll
    for (int kf = 0; kf < 8; kf++) qf[kf] = *(const f16x8*)(qrow + kf * 32);
  }
  const f16* Kb = Kh + (size_t)b * N_DIM * C_DIM;
  const f16* Vb = Vh + (size_t)b * C_DIM * N_DIM;
  f16* Pw = smem + P_OFF + w * 16 * PSTR;

  const float LOG2E = 1.4426950408889634f;
  float m = -3.0e38f, l = 0.0f;
  f32x4 acc[16];
#pragma unroll
  for (int ct = 0; ct < 16; ct++) acc[ct] = (f32x4){0.f, 0.f, 0.f, 0.f};

  // prologue: DMA tile 0 -> buf0 (pre-swizzled global source chunks)
  {
#pragma unroll
    for (int it = 0; it < 4; it++) {
      int p = w * 4 + it;
      int krsw = (2 * it + (lane >> 5)) & 7;     // (2p+(l>>5))&7, since 8w==0 mod 8
      dma16(Kb + (size_t)(2 * p + (lane >> 5)) * C_DIM + (((lane & 31) ^ krsw) * 8),
            smem + K0_OFF + p * 512);
      dma16(Vb + (size_t)(p * 8 + (lane >> 3)) * N_DIM + (((lane & 7) ^ (lane >> 3)) * 8),
            smem + V0_OFF + p * 512);
    }
  }
  __syncthreads();

  for (int t = 0; t < NT; t++) {
    const f16* Kc = smem + ((t & 1) ? K1_OFF : K0_OFF);
    const f16* Vc = smem + ((t & 1) ? V1_OFF : V0_OFF);

    // issue DMA for tile t+1 into the other buffer (drained at the barrier)
    if (t + 1 < NT) {
      f16* Kn = smem + ((t & 1) ? K0_OFF : K1_OFF);
      f16* Vn = smem + ((t & 1) ? V0_OFF : V1_OFF);
      const int jt = (t + 1) * JT;
      const f16* kg = Kb + (size_t)jt * C_DIM;
      const f16* vg = Vb + jt;
#pragma unroll
      for (int it = 0; it < 4; it++) {
        int p = w * 4 + it;
        int krsw = (2 * it + (lane >> 5)) & 7;
        dma16(kg + (size_t)(2 * p + (lane >> 5)) * C_DIM + (((lane & 31) ^ krsw) * 8),
              Kn + p * 512);
        dma16(vg + (size_t)(p * 8 + (lane >> 3)) * N_DIM + (((lane & 7) ^ (lane >> 3)) * 8),
              Vn + p * 512);
      }
    }

    // ---- S^T for this wave's j-half: rows j = wj*32 + sub*16 + (quad*4+reg) ----
    f32x4 s[2];
#pragma unroll
    for (int sub = 0; sub < 2; sub++) {
      f32x4 ss = {0.f, 0.f, 0.f, 0.f};
      const f16* krow = Kc + (wj * 32 + sub * 16 + li) * 256;  // row&7 == li&7
#pragma unroll
      for (int kf = 0; kf < 8; kf++) {
        f16x8 kfr = *(const f16x8*)(krow + ksl[kf]);
        ss = __builtin_amdgcn_mfma_f32_16x16x32_f16(kfr, qf[kf], ss, 0, 0, 0);
      }
      s[sub] = ss;
    }

    // ---- online softmax over this j-half (per query col li) ----
    float tm = fmaxf(fmaxf(fmaxf(s[0][0], s[0][1]), fmaxf(s[0][2], s[0][3])),
                     fmaxf(fmaxf(s[1][0], s[1][1]), fmaxf(s[1][2], s[1][3])));
    tm = fmaxf(tm, __shfl_xor(tm, 16));
    tm = fmaxf(tm, __shfl_xor(tm, 32));
    float nm = fmaxf(m, tm);
    float alpha = exp2f((m - nm) * LOG2E);
    m = nm;
    if (__any(alpha < 1.0f)) {      // wave-uniform skip when max unchanged
      l *= alpha;
#pragma unroll
      for (int ct = 0; ct < 16; ct++) {
        acc[ct][0] *= alpha; acc[ct][1] *= alpha;
        acc[ct][2] *= alpha; acc[ct][3] *= alpha;
      }
    }
#pragma unroll
    for (int sub = 0; sub < 2; sub++) {
      float p0 = exp2f((s[sub][0] - m) * LOG2E);
      float p1 = exp2f((s[sub][1] - m) * LOG2E);
      float p2 = exp2f((s[sub][2] - m) * LOG2E);
      float p3 = exp2f((s[sub][3] - m) * LOG2E);
      l += (p0 + p1) + (p2 + p3);
      *(f16x4*)(Pw + li * PSTR + sub * 16 + quad * 4) =
          (f16x4){(f16)p0, (f16)p1, (f16)p2, (f16)p3};
    }

    // ---- PV (half): O^T[c][i] += V[c][j-half] P^T[j-half][i], k = 32 ----
    f16x8 pf = *(const f16x8*)(Pw + li * PSTR + quad * 8);
#pragma unroll
    for (int ct = 0; ct < 16; ct++) {
      const f16* vrow = Vc + (ct * 16 + li) * 64;
      f16x8 v = *(const f16x8*)(vrow + vsl);
      acc[ct] = __builtin_amdgcn_mfma_f32_16x16x32_f16(v, pf, acc[ct], 0, 0, 0);
    }

    __syncthreads();   // waits readers of current bufs AND drains next-tile DMA
  }

  // ---- reduce l across quads; merge j-half partials via LDS (K/V region reused) ----
  l += __shfl_xor(l, 16);
  l += __shfl_xor(l, 32);

  float* mrg = (float*)smem;
  if (wj == 1) {
    const int u = wq;
    float* base = mrg + u * MRG_WSTR + li * MRG_CSTR;
#pragma unroll
    for (int ct = 0; ct < 16; ct++)
      *(f32x4*)(base + ct * 16 + quad * 4) = acc[ct];
    if (lane < 16) {
      mrg[ML_OFF + u * 32 + li] = m;
      mrg[ML_OFF + u * 32 + 16 + li] = l;
    }
  }
  __syncthreads();
  if (wj == 0) {
    const int u = wq;
    const float m_b = mrg[ML_OFF + u * 32 + li];
    const float l_b = mrg[ML_OFF + u * 32 + 16 + li];
    const float M = fmaxf(m, m_b);
    const float aa = exp2f((m - M) * LOG2E);
    const float ab = exp2f((m_b - M) * LOG2E);
    const float lm = aa * l + ab * l_b;
    const float scale = gamma_p[0] / lm;
    const float* base = mrg + u * MRG_WSTR + li * MRG_CSTR;

    const float* xb = x + (size_t)b * C_DIM * N_DIM;
    float* ob = out + (size_t)b * C_DIM * N_DIM;
    const int icol = ibase + li;
#pragma unroll
    for (int ct = 0; ct < 16; ct++) {
      f32x4 accb = *(const f32x4*)(base + ct * 16 + quad * 4);
#pragma unroll
      for (int r = 0; r < 4; r++) {
        size_t off = (size_t)(ct * 16 + quad * 4 + r) * N_DIM + icol;
        ob[off] = (acc[ct][r] * aa + accb[r] * ab) * scale + xb[off];
      }
    }
  }
}

extern "C" void kernel_launch(void* const* d_in, const int* in_sizes, int n_in,
                              void* d_out, int out_size, void* d_ws, size_t ws_size,
                              hipStream_t stream) {
  const float* x     = (const float*)d_in[0];
  const float* Wq    = (const float*)d_in[1];
  const float* bq    = (const float*)d_in[2];
  const float* Wk    = (const float*)d_in[3];
  const float* bk    = (const float*)d_in[4];
  const float* Wv    = (const float*)d_in[5];
  const float* bv    = (const float*)d_in[6];
  const float* gamma = (const float*)d_in[7];
  float* out = (float*)d_out;

  // workspace: Qh 8MB | Kh 8MB | Vh 8MB | Wh 384KB  (~24.4 MB)
  char* ws = (char*)d_ws;
  f16* Qh = (f16*)(ws);
  f16* Kh = (f16*)(ws + (size_t)8  * 1024 * 1024);
  f16* Vh = (f16*)(ws + (size_t)16 * 1024 * 1024);
  f16* Wh = (f16*)(ws + (size_t)24 * 1024 * 1024);

  k_cast_w<<<dim3(768), 256, 0, stream>>>(Wq, Wk, Wv, Wh);
  k_qkv<<<dim3(64, 4), 512, 0, stream>>>(x, Wh, bq, bk, bv, Qh, Kh, Vh);
  k_attn<<<dim3(64, 4), 512, 0, stream>>>(Qh, Kh, Vh, x, gamma, out);
}